// Round 1
// baseline (1304.725 us; speedup 1.0000x reference)
//
#include <hip/hip_runtime.h>
#include <math.h>

#define B_ROWS 8192
#define V_COLS 32000
#define K_NEG  5
#define S_DOM  100
#define EPSF   1e-10f

// One block per row: max-reduce the 32000-wide row, then thread 0 computes
// the sampled-softmax row loss. Row losses -> ws; second kernel reduces.
__global__ __launch_bounds__(256) void blackout_row_kernel(
    const float* __restrict__ yHat,
    const float* __restrict__ prob,
    const int*   __restrict__ y,
    const int*   __restrict__ ind,
    float*       __restrict__ row_loss)
{
    const int r   = blockIdx.x;
    const int tid = threadIdx.x;
    const float* __restrict__ row = yHat + (size_t)r * V_COLS;

    // ---- streaming max over the row (float4, coalesced) ----
    const float4* __restrict__ row4 = (const float4*)row;
    float m = -INFINITY;
    #pragma unroll 4
    for (int i = tid; i < V_COLS / 4; i += 256) {
        float4 v = row4[i];
        m = fmaxf(m, fmaxf(fmaxf(v.x, v.y), fmaxf(v.z, v.w)));
    }
    // wave64 butterfly
    #pragma unroll
    for (int off = 32; off > 0; off >>= 1)
        m = fmaxf(m, __shfl_down(m, off, 64));
    __shared__ float smax[4];
    if ((tid & 63) == 0) smax[tid >> 6] = m;
    __syncthreads();

    // ---- tail: gathers + tiny math, thread 0 only ----
    if (tid == 0) {
        const float mm = fmaxf(fmaxf(smax[0], smax[1]), fmaxf(smax[2], smax[3]));

        const int yy = y[r];
        const float* __restrict__ prow = prob + (size_t)yy * S_DOM;

        float p[K_NEG], comp[K_NEG];
        float q = INFINITY;
        #pragma unroll
        for (int j = 0; j < K_NEG; ++j) {
            const int ij = ind[r * K_NEG + j];     // in [0, 100)
            const float pv = 1.0f / prow[ij];
            p[j] = pv;
            q = fminf(q, pv);
            comp[j] = row[ij] - mm;
        }
        const float Yg = row[yy] - mm;

        float v[K_NEG + 1];
        v[0] = q * expf(Yg);
        float sum = v[0];
        #pragma unroll
        for (int j = 0; j < K_NEG; ++j) {
            v[j + 1] = p[j] * expf(comp[j]);
            sum += v[j + 1];
        }
        const float inv_sum = 1.0f / sum;

        // loss_r = log(out0+eps) + sum_{j>=1} log(1 - out_j + eps)
        float lr = logf(v[0] * inv_sum + EPSF);
        #pragma unroll
        for (int j = 1; j <= K_NEG; ++j)
            lr += logf(1.0f - v[j] * inv_sum + EPSF);

        row_loss[r] = lr;
    }
}

__global__ __launch_bounds__(256) void blackout_reduce_kernel(
    const float* __restrict__ row_loss,
    float*       __restrict__ out)
{
    const int tid = threadIdx.x;
    float s = 0.0f;
    for (int i = tid; i < B_ROWS; i += 256)
        s += row_loss[i];
    #pragma unroll
    for (int off = 32; off > 0; off >>= 1)
        s += __shfl_down(s, off, 64);
    __shared__ float sh[4];
    if ((tid & 63) == 0) sh[tid >> 6] = s;
    __syncthreads();
    if (tid == 0) {
        const float tot = sh[0] + sh[1] + sh[2] + sh[3];
        out[0] = -tot / (float)(B_ROWS * (K_NEG + 1));
    }
}

extern "C" void kernel_launch(void* const* d_in, const int* in_sizes, int n_in,
                              void* d_out, int out_size, void* d_ws, size_t ws_size,
                              hipStream_t stream) {
    const float* yHat = (const float*)d_in[0];   // [8192, 32000] f32
    const float* prob = (const float*)d_in[1];   // [32000, 100] f32
    const int*   y    = (const int*)d_in[2];     // [8192]
    const int*   ind  = (const int*)d_in[3];     // [8192, 5]
    float* out = (float*)d_out;                  // scalar
    float* row_loss = (float*)d_ws;              // 8192 floats scratch

    blackout_row_kernel<<<B_ROWS, 256, 0, stream>>>(yHat, prob, y, ind, row_loss);
    blackout_reduce_kernel<<<1, 256, 0, stream>>>(row_loss, out);
}